// Round 4
// baseline (733.426 us; speedup 1.0000x reference)
//
#include <hip/hip_runtime.h>
#include <hip/hip_bf16.h>
#include <stdint.h>

// Problem sizes (fixed by the reference)
#define IN_F  4096
#define OUT_F 4096
#define NROWS 16384
#define NT    (IN_F / 64)   // 64 K-tiles of BK=64

typedef unsigned short u16;
typedef unsigned long long u64;
typedef __bf16 bf16x8 __attribute__((ext_vector_type(8)));
typedef float  f32x4  __attribute__((ext_vector_type(4)));
typedef u16    u16x8  __attribute__((ext_vector_type(8)));

#define BAR()   asm volatile("s_barrier" ::: "memory")
#define LGKM0() asm volatile("s_waitcnt lgkmcnt(0)" ::: "memory")
#define VM4()   asm volatile("s_waitcnt vmcnt(4)" ::: "memory")

// fp32 -> bf16, round-to-nearest-even (finite inputs only)
__device__ __forceinline__ u16 f2bf(float x) {
    union { float f; uint32_t u; } c; c.f = x;
    uint32_t u = c.u;
    return (u16)((u + 0x7FFFu + ((u >> 16) & 1u)) >> 16);
}

// async global->LDS, 16B per lane. LDS dest = wave-uniform base + lane*16.
__device__ __forceinline__ void gload_lds16(const void* g, void* l) {
    __builtin_amdgcn_global_load_lds(
        (const __attribute__((address_space(1))) void*)g,
        (__attribute__((address_space(3))) void*)l, 16, 0, 0);
}

__device__ __forceinline__ u16 sgn_bf16(float v) {
    return v > 0.f ? 0x3F80 : (v < 0.f ? 0xBF80 : 0);
}

// --- Prep 1 (fast path): per-row alpha = mean(|W|) AND bit-packed signs.
// Wbits[row][kword] bit b = (W[row][kword*64+b] > 0). Whole B = 2 MB ->
// L2-resident in every XCD (the round-3 fetch analysis showed the bf16
// B+A streams were the 2 TB/s L2-fill bottleneck).
__global__ void prep_wbits_kernel(const float* __restrict__ W,
                                  float* __restrict__ alpha,
                                  u64* __restrict__ Wbits) {
    const int row = blockIdx.x;                       // 0..OUT_F-1
    const int wave = threadIdx.x >> 6, lane = threadIdx.x & 63;
    const float* wr = W + (size_t)row * IN_F;
    float s = 0.f;
#pragma unroll 4
    for (int it = 0; it < 16; ++it) {
        const int kword = it * 4 + wave;              // 64 words per row
        float v = __builtin_nontemporal_load(wr + kword * 64 + lane);
        s += fabsf(v);
        u64 m = __ballot(v > 0.f);                    // 64-bit wave mask
        if (lane == 0) Wbits[(size_t)row * 64 + kword] = m;
    }
    for (int off = 32; off > 0; off >>= 1) s += __shfl_down(s, off);
    __shared__ float red[4];
    if (lane == 0) red[wave] = s;
    __syncthreads();
    if (threadIdx.x == 0)
        alpha[row] = (red[0] + red[1] + red[2] + red[3]) * (1.0f / IN_F);
}

// --- Prep 2: x fp32 -> bf16 (RNE), chunk-swizzled for T2 (c8 ^= row&7) ---
__global__ void convx_kernel(const float* __restrict__ X, u16* __restrict__ O,
                             int swz) {
    const size_t idx = (size_t)blockIdx.x * 256 + threadIdx.x; // 16B out chunk
    const int row = (int)(idx >> 9);                 // 512 chunks per row
    const int q = (int)idx & 511;
    const int g = q >> 3, c8 = q & 7;
    const int c8s = swz ? (c8 ^ (row & 7)) : c8;
    const f32x4* src = reinterpret_cast<const f32x4*>(
        X + (size_t)row * IN_F + g * 64 + c8s * 8);
    f32x4 a = __builtin_nontemporal_load(src);
    f32x4 b = __builtin_nontemporal_load(src + 1);
    u16x8 r;
    r[0] = f2bf(a[0]); r[1] = f2bf(a[1]); r[2] = f2bf(a[2]); r[3] = f2bf(a[3]);
    r[4] = f2bf(b[0]); r[5] = f2bf(b[1]); r[6] = f2bf(b[2]); r[7] = f2bf(b[3]);
    reinterpret_cast<u16x8*>(O)[idx] = r;
}

// ============================================================================
// 256x256 GEMM, bit-B edition. Y[m][n] = alpha[n]*sum_k Xbf[m][k]*sgn[n][k]+bias[n]
// - A (Xbf): LDS triple-buffer, 3 x 32KB, sigma=+2 prefetch via global_load_lds,
//   T2 pre-swizzled global + XOR'd ds_read (0 conflicts, verified r2/r3).
// - B (Wbits): NO LDS. Per K-tile each lane loads 4 u64 (its 4 frag-columns'
//   64 k-bits) from the L2-resident 2MB bitmap, expands to +-1 bf16 frags in
//   registers (~128 VALU/lane/tile; VALUBusy was 16%).
// - Partition: xcd = wg&7 owns m-tiles [8*xcd, 8*xcd+8) x ALL 16 n-tiles.
//   i = wg>>3: n = i&15 fast -> co-resident WGs per XCD = 4m x 16n, K-lockstep
//   -> 16-way L2 sharing of each A-slab. Per-XCD L2 fill ~ 16MB A + 2MB B.
// - vmcnt ledger (per wave, per tile t): phi0 issues 4 B-loads(t+1);
//   phi1/phi2 issue 2+2 A-stages(t+2). Boundary VM4: completes A(t+1)+B(t+1),
//   leaves A(t+2)x4 in flight. Prologue: B(0),A(0),A(1) then VM4 -> A(1) rides.
// ============================================================================
__global__ __launch_bounds__(512, 2) void gemm8_kernel(
    const u16* __restrict__ Xbf, const u64* __restrict__ Wbits,
    const float* __restrict__ alpha, const float* __restrict__ bias,
    float* __restrict__ Y) {
    __shared__ u16 lds_[49152];   // 96 KiB: 3 A-tile buffers of 16384 u16

    const int tid  = threadIdx.x;
    const int lane = tid & 63, wave = tid >> 6;
    const int wm = wave >> 2, wn = wave & 3;      // 2(M) x 4(N) waves
    const int lrow = lane & 15;

    const int wg = blockIdx.x;
    const int i  = wg >> 3;                       // 0..127 within XCD
    const int m0 = (((wg & 7) << 3) | (i >> 4)) << 8;   // xcd*8 + m_local
    const int n0 = (i & 15) << 8;

    // T2 swizzled ds_read k-offsets (u16 units)
    const int q0 = ((lane >> 4) << 3) ^ ((lrow & 7) << 3);
    const int q1 = q0 ^ 32;

    f32x4 acc[8][4];
#pragma unroll
    for (int a = 0; a < 8; ++a)
#pragma unroll
        for (int b = 0; b < 4; ++b) acc[a][b] = (f32x4){0.f, 0.f, 0.f, 0.f};

    // stage one 128-row half of A K-tile th into buf (2 gload_lds16 / thread)
    auto stageA = [&](int th, int half, u16* buf) {
        if (th >= NT) return;
#pragma unroll
        for (int t2 = 0; t2 < 2; ++t2) {
            const int c = half * 1024 + t2 * 512 + tid;   // 16B chunk idx
            const int row = c >> 3, c8 = c & 7;
            gload_lds16(Xbf + (size_t)(m0 + row) * IN_F + th * 64 + c8 * 8,
                        buf + c * 8);
        }
    };

    u64 wcur[4], wnext[4];
    auto loadB = [&](int th, u64* w) {
        if (th >= NT) return;
#pragma unroll
        for (int nf = 0; nf < 4; ++nf)
            w[nf] = Wbits[(size_t)(n0 + wn * 64 + nf * 16 + lrow) * 64 + th];
    };

    u16* b0 = lds_;
    u16* b1 = lds_ + 16384;
    u16* b2 = lds_ + 32768;

    // prologue: B(0) first, then A(0), A(1) -> VM4 completes B(0)+A(0),
    // leaves A(1)x4 in flight (steady-state invariant).
    loadB(0, wcur);
    stageA(0, 0, b0); stageA(0, 1, b0);
    stageA(1, 0, b1); stageA(1, 1, b1);
    VM4(); BAR();

    u16* br = b0; u16* bn = b1; u16* bs = b2;
    const int sh = (lane >> 4) << 3;              // bit offset for kk=0 byte

    for (int t = 0; t < NT; ++t) {
        const u16* Ab = br + wm * 8192 + lrow * 64;
        bf16x8 a0[4][2], a1[4][2], bfr[4][2];

        // --- phi0: ds_read a0; issue B(t+1); expand bfr from wcur ---
#pragma unroll
        for (int mm = 0; mm < 4; ++mm) {
            a0[mm][0] = *reinterpret_cast<const bf16x8*>(Ab + mm * 1024 + q0);
            a0[mm][1] = *reinterpret_cast<const bf16x8*>(Ab + mm * 1024 + q1);
        }
        loadB(t + 1, wnext);
#pragma unroll
        for (int nf = 0; nf < 4; ++nf)
#pragma unroll
            for (int kk = 0; kk < 2; ++kk) {
                unsigned bb = (unsigned)(wcur[nf] >> (sh + kk * 32)) & 0xFFu;
                union { unsigned u[4]; bf16x8 v; } r;
#pragma unroll
                for (int e = 0; e < 4; ++e)
                    r.u[e] = (((bb >> (2 * e)) & 1u) ? 0x3F80u : 0xBF80u)
                           | (((bb >> (2 * e + 1)) & 1u) ? 0x3F800000u : 0xBF800000u);
                bfr[nf][kk] = r.v;
            }
        BAR(); LGKM0();
        __builtin_amdgcn_s_setprio(1);
#pragma unroll
        for (int mm = 0; mm < 4; ++mm)
#pragma unroll
            for (int nn = 0; nn < 2; ++nn) {
                acc[mm][nn] = __builtin_amdgcn_mfma_f32_16x16x32_bf16(a0[mm][0], bfr[nn][0], acc[mm][nn], 0, 0, 0);
                acc[mm][nn] = __builtin_amdgcn_mfma_f32_16x16x32_bf16(a0[mm][1], bfr[nn][1], acc[mm][nn], 0, 0, 0);
            }
        __builtin_amdgcn_s_setprio(0);
        BAR();

        // --- phi1: ds_read a1; stage A(t+2) half-lo; MFMA q1 ---
#pragma unroll
        for (int mm = 0; mm < 4; ++mm) {
            a1[mm][0] = *reinterpret_cast<const bf16x8*>(Ab + (4 + mm) * 1024 + q0);
            a1[mm][1] = *reinterpret_cast<const bf16x8*>(Ab + (4 + mm) * 1024 + q1);
        }
        stageA(t + 2, 0, bs);
        BAR();
        __builtin_amdgcn_s_setprio(1);
#pragma unroll
        for (int mm = 0; mm < 4; ++mm)
#pragma unroll
            for (int nn = 0; nn < 2; ++nn) {
                acc[mm][2 + nn] = __builtin_amdgcn_mfma_f32_16x16x32_bf16(a0[mm][0], bfr[2 + nn][0], acc[mm][2 + nn], 0, 0, 0);
                acc[mm][2 + nn] = __builtin_amdgcn_mfma_f32_16x16x32_bf16(a0[mm][1], bfr[2 + nn][1], acc[mm][2 + nn], 0, 0, 0);
            }
        __builtin_amdgcn_s_setprio(0);
        BAR();

        // --- phi2: stage A(t+2) half-hi; drain a1; MFMA q2 ---
        stageA(t + 2, 1, bs);
        BAR(); LGKM0();
        __builtin_amdgcn_s_setprio(1);
#pragma unroll
        for (int mm = 0; mm < 4; ++mm)
#pragma unroll
            for (int nn = 0; nn < 2; ++nn) {
                acc[4 + mm][nn] = __builtin_amdgcn_mfma_f32_16x16x32_bf16(a1[mm][0], bfr[nn][0], acc[4 + mm][nn], 0, 0, 0);
                acc[4 + mm][nn] = __builtin_amdgcn_mfma_f32_16x16x32_bf16(a1[mm][1], bfr[nn][1], acc[4 + mm][nn], 0, 0, 0);
            }
        __builtin_amdgcn_s_setprio(0);
        BAR();

        // --- phi3: MFMA q3; boundary vmcnt(4) ---
        __builtin_amdgcn_s_setprio(1);
#pragma unroll
        for (int mm = 0; mm < 4; ++mm)
#pragma unroll
            for (int nn = 0; nn < 2; ++nn) {
                acc[4 + mm][2 + nn] = __builtin_amdgcn_mfma_f32_16x16x32_bf16(a1[mm][0], bfr[2 + nn][0], acc[4 + mm][2 + nn], 0, 0, 0);
                acc[4 + mm][2 + nn] = __builtin_amdgcn_mfma_f32_16x16x32_bf16(a1[mm][1], bfr[2 + nn][1], acc[4 + mm][2 + nn], 0, 0, 0);
            }
        __builtin_amdgcn_s_setprio(0);
        VM4(); BAR();

        // rotate buffers, promote B regs
        u16* tp = br; br = bn; bn = bs; bs = tp;
#pragma unroll
        for (int nf = 0; nf < 4; ++nf) wcur[nf] = wnext[nf];
    }

    // epilogue: y = acc*alpha[col] + bias[col]; C/D: col=lane&15, row=(lane>>4)*4+r
#pragma unroll
    for (int nf = 0; nf < 4; ++nf) {
        const int col = n0 + wn * 64 + nf * 16 + lrow;
        const float al = alpha[col], bi = bias[col];
#pragma unroll
        for (int mf = 0; mf < 8; ++mf) {
            const int rbase = m0 + wm * 128 + mf * 16 + ((lane >> 4) << 2);
#pragma unroll
            for (int r = 0; r < 4; ++r)
                __builtin_nontemporal_store(acc[mf][nf][r] * al + bi,
                    &Y[(size_t)(rbase + r) * OUT_F + col]);
        }
    }
}

// ============================================================================
// Fallback (small workspace): round-1 128x128 kernel, A reg-staged from fp32,
// bf16 Wsign unswizzled. Verified correct in round 1.
// ============================================================================
__global__ void prep_w_kernel(const float* __restrict__ W,
                              float* __restrict__ alpha,
                              u16* __restrict__ S) {
    const int row = blockIdx.x;
    const float* wr = W + (size_t)row * IN_F;
    float s = 0.f;
    for (int c = threadIdx.x; c < 512; c += 256) {
        const f32x4* src = reinterpret_cast<const f32x4*>(wr + c * 8);
        f32x4 v0 = __builtin_nontemporal_load(src);
        f32x4 v1 = __builtin_nontemporal_load(src + 1);
        s += fabsf(v0[0]) + fabsf(v0[1]) + fabsf(v0[2]) + fabsf(v0[3])
           + fabsf(v1[0]) + fabsf(v1[1]) + fabsf(v1[2]) + fabsf(v1[3]);
        u16x8 r;
        r[0] = sgn_bf16(v0[0]); r[1] = sgn_bf16(v0[1]);
        r[2] = sgn_bf16(v0[2]); r[3] = sgn_bf16(v0[3]);
        r[4] = sgn_bf16(v1[0]); r[5] = sgn_bf16(v1[1]);
        r[6] = sgn_bf16(v1[2]); r[7] = sgn_bf16(v1[3]);
        *reinterpret_cast<u16x8*>(S + (size_t)row * IN_F + c * 8) = r;
    }
    for (int off = 32; off > 0; off >>= 1) s += __shfl_down(s, off);
    __shared__ float red[4];
    const int wave = threadIdx.x >> 6, lane = threadIdx.x & 63;
    if (lane == 0) red[wave] = s;
    __syncthreads();
    if (threadIdx.x == 0)
        alpha[row] = (red[0] + red[1] + red[2] + red[3]) * (1.0f / IN_F);
}

__global__ __launch_bounds__(256) void gemm_fallback(
    const float* __restrict__ X, const u16* __restrict__ Wsign,
    const float* __restrict__ alpha, const float* __restrict__ bias,
    float* __restrict__ Y) {
    __shared__ u16 Alds[128 * 64];
    __shared__ u16 Blds[128 * 64];

    const int tid = threadIdx.x;
    const int n0 = blockIdx.x * 128;
    const int m0 = blockIdx.y * 128;
    const int wave = tid >> 6, lane = tid & 63;
    const int wm = wave >> 1, wn = wave & 1;
    const int lrow = lane & 15;
    const int lk8 = (lane >> 4) * 8;

    f32x4 acc[4][4];
#pragma unroll
    for (int a = 0; a < 4; ++a)
#pragma unroll
        for (int b = 0; b < 4; ++b) acc[a][b] = (f32x4){0.f, 0.f, 0.f, 0.f};

    for (int kt = 0; kt < IN_F; kt += 64) {
#pragma unroll
        for (int j = 0; j < 4; ++j) {
            const int idx = j * 256 + tid;
            const int row = idx >> 3, c8 = idx & 7;
            gload_lds16(Wsign + (size_t)(n0 + row) * IN_F + kt + c8 * 8,
                        &Blds[idx * 8]);
        }
#pragma unroll
        for (int j = 0; j < 4; ++j) {
            const int idx = j * 256 + tid;
            const int row = idx >> 3, c8 = idx & 7;
            const float* src = X + (size_t)(m0 + row) * IN_F + kt + c8 * 8;
            float4 v0 = *reinterpret_cast<const float4*>(src);
            float4 v1 = *reinterpret_cast<const float4*>(src + 4);
            u16x8 r;
            r[0] = f2bf(v0.x); r[1] = f2bf(v0.y); r[2] = f2bf(v0.z); r[3] = f2bf(v0.w);
            r[4] = f2bf(v1.x); r[5] = f2bf(v1.y); r[6] = f2bf(v1.z); r[7] = f2bf(v1.w);
            *reinterpret_cast<u16x8*>(&Alds[idx * 8]) = r;
        }
        __syncthreads();
#pragma unroll
        for (int kk = 0; kk < 2; ++kk) {
            bf16x8 af[4], bfv[4];
#pragma unroll
            for (int mf = 0; mf < 4; ++mf)
                af[mf] = *reinterpret_cast<const bf16x8*>(
                    &Alds[(wm * 64 + mf * 16 + lrow) * 64 + kk * 32 + lk8]);
#pragma unroll
            for (int nf = 0; nf < 4; ++nf)
                bfv[nf] = *reinterpret_cast<const bf16x8*>(
                    &Blds[(wn * 64 + nf * 16 + lrow) * 64 + kk * 32 + lk8]);
#pragma unroll
            for (int mf = 0; mf < 4; ++mf)
#pragma unroll
                for (int nf = 0; nf < 4; ++nf)
                    acc[mf][nf] = __builtin_amdgcn_mfma_f32_16x16x32_bf16(
                        af[mf], bfv[nf], acc[mf][nf], 0, 0, 0);
        }
        __syncthreads();
    }
#pragma unroll
    for (int nf = 0; nf < 4; ++nf) {
        const int col = n0 + wn * 64 + nf * 16 + lrow;
        const float al = alpha[col], bi = bias[col];
#pragma unroll
        for (int mf = 0; mf < 4; ++mf) {
            const int rbase = m0 + wm * 64 + mf * 16 + (lane >> 4) * 4;
#pragma unroll
            for (int r = 0; r < 4; ++r)
                __builtin_nontemporal_store(acc[mf][nf][r] * al + bi,
                    &Y[(size_t)(rbase + r) * OUT_F + col]);
        }
    }
}

extern "C" void kernel_launch(void* const* d_in, const int* in_sizes, int n_in,
                              void* d_out, int out_size, void* d_ws, size_t ws_size,
                              hipStream_t stream) {
    const float* X    = (const float*)d_in[0];
    const float* W    = (const float*)d_in[1];
    const float* bias = (const float*)d_in[2];
    float* Y = (float*)d_out;

    char* ws = (char*)d_ws;
    float* alpha = (float*)ws;                               // 16 KB
    const size_t WBITS_OFF = 16384;
    const size_t XBF_OFF   = WBITS_OFF + (size_t)OUT_F * (IN_F / 8); // +2 MB
    const size_t need_fast = XBF_OFF + (size_t)NROWS * IN_F * 2;     // +128 MB
    const size_t need_safe = 16384 + (size_t)OUT_F * IN_F * 2;       // 32 MB path

    if (ws_size >= need_fast) {
        u64* Wbits = (u64*)(ws + WBITS_OFF);
        u16* Xbf   = (u16*)(ws + XBF_OFF);
        prep_wbits_kernel<<<OUT_F, 256, 0, stream>>>(W, alpha, Wbits);
        convx_kernel<<<(size_t)NROWS * IN_F / 8 / 256, 256, 0, stream>>>(X, Xbf, 1);
        gemm8_kernel<<<dim3(1024), 512, 0, stream>>>(Xbf, Wbits, alpha, bias, Y);
    } else {
        u16* Wsign = (u16*)(ws + 16384);
        prep_w_kernel<<<OUT_F, 256, 0, stream>>>(W, alpha, Wsign);
        dim3 grid(OUT_F / 128, NROWS / 128);
        gemm_fallback<<<grid, 256, 0, stream>>>(X, Wsign, alpha, bias, Y);
    }
}